// Round 1
// baseline (1136.496 us; speedup 1.0000x reference)
//
#include <hip/hip_runtime.h>
#include <hip/hip_bf16.h>

#define N_NODES 50000
#define N_EDGES 500000
#define IN_CH 128
#define OUT_CH 128
#define N_TYPES 2
#define NEG_SLOPE 0.2f
#define EPS_F 1e-16f

// ---------------------------------------------------------------------------
// Kernel 1: fused GEMM
//   hall[n][t][o] = sum_k x[n][k] * weight[t][k][o]      (t = 0,1)
//   out[n][o]     = sum_k x[n][k] * root_w[o][k] + root_b[o]
// Treated as C[50000,384] = X[50000,128] @ B[128,384] with B chunked by 128
// columns; chunk 2 is root_w transposed during LDS staging.
// ---------------------------------------------------------------------------
#define TM 32          // nodes per block
#define BS_STRIDE 132  // padded LDS stride (floats); 132*4 bytes keeps 16B align

__global__ __launch_bounds__(256) void gemm_kernel(
    const float* __restrict__ x, const float* __restrict__ weight,
    const float* __restrict__ root_w, const float* __restrict__ root_b,
    float* __restrict__ hall, float* __restrict__ out)
{
    __shared__ float xs[TM][IN_CH];
    __shared__ float Bs[64][BS_STRIDE];

    const int tid = threadIdx.x;
    const int block_n0 = blockIdx.x * TM;
    const int nb = tid >> 5;   // 0..7 : group of 4 nodes
    const int ob = tid & 31;   // 0..31: group of 4 outputs
    const int n0 = nb * 4;
    const int o0 = ob * 4;

    // stage x tile: 32 nodes x 128 ch = 1024 float4, 4 per thread (coalesced)
    {
        const float4* xg = (const float4*)x;
        #pragma unroll
        for (int i = 0; i < 4; ++i) {
            int idx = tid + i * 256;          // 0..1023
            int n = idx >> 5;                 // node in tile
            int c4 = idx & 31;                // float4 index in row
            int gn = block_n0 + n;
            float4 v = make_float4(0.f, 0.f, 0.f, 0.f);
            if (gn < N_NODES) v = xg[(size_t)gn * 32 + c4];
            *(float4*)&xs[n][c4 * 4] = v;
        }
    }

    for (int c = 0; c < 3; ++c) {
        float acc[4][4] = {};
        for (int kh = 0; kh < 2; ++kh) {
            __syncthreads();   // protects xs (first iter) / Bs reuse
            if (c < 2) {
                // weight[c][kh*64 + kk][o] -> Bs[kk][o]; rows contiguous
                const float4* wg =
                    (const float4*)(weight + (size_t)c * IN_CH * OUT_CH + (size_t)kh * 64 * OUT_CH);
                #pragma unroll
                for (int i = 0; i < 8; ++i) {
                    int idx = tid + i * 256;  // 0..2047 float4s
                    int kk = idx >> 5;
                    int c4 = idx & 31;
                    float4 v = wg[kk * 32 + c4];
                    *(float4*)&Bs[kk][c4 * 4] = v;
                }
            } else {
                // root_w[j][kh*64 + kk] -> Bs[kk][j] (transpose while staging)
                for (int i = 0; i < 32; ++i) {
                    int idx = tid + i * 256;  // 0..8191
                    int j = idx >> 6;         // output channel 0..127
                    int kk = idx & 63;
                    Bs[kk][j] = root_w[(size_t)j * IN_CH + kh * 64 + kk];
                }
            }
            __syncthreads();

            #pragma unroll 4
            for (int kk = 0; kk < 64; ++kk) {
                float4 bv = *(const float4*)&Bs[kk][o0];
                float x0 = xs[n0 + 0][kh * 64 + kk];
                float x1 = xs[n0 + 1][kh * 64 + kk];
                float x2 = xs[n0 + 2][kh * 64 + kk];
                float x3 = xs[n0 + 3][kh * 64 + kk];
                acc[0][0] += x0 * bv.x; acc[0][1] += x0 * bv.y; acc[0][2] += x0 * bv.z; acc[0][3] += x0 * bv.w;
                acc[1][0] += x1 * bv.x; acc[1][1] += x1 * bv.y; acc[1][2] += x1 * bv.z; acc[1][3] += x1 * bv.w;
                acc[2][0] += x2 * bv.x; acc[2][1] += x2 * bv.y; acc[2][2] += x2 * bv.z; acc[2][3] += x2 * bv.w;
                acc[3][0] += x3 * bv.x; acc[3][1] += x3 * bv.y; acc[3][2] += x3 * bv.z; acc[3][3] += x3 * bv.w;
            }
        }

        if (c < 2) {
            #pragma unroll
            for (int i = 0; i < 4; ++i) {
                int gn = block_n0 + n0 + i;
                if (gn < N_NODES) {
                    float4 v = make_float4(acc[i][0], acc[i][1], acc[i][2], acc[i][3]);
                    *(float4*)&hall[((size_t)gn * 2 + c) * 128 + o0] = v;
                }
            }
        } else {
            float4 bias = *(const float4*)&root_b[o0];
            #pragma unroll
            for (int i = 0; i < 4; ++i) {
                int gn = block_n0 + n0 + i;
                if (gn < N_NODES) {
                    float4 v = make_float4(acc[i][0] + bias.x, acc[i][1] + bias.y,
                                           acc[i][2] + bias.z, acc[i][3] + bias.w);
                    *(float4*)&out[(size_t)gn * 128 + o0] = v;
                }
            }
        }
    }
}

// ---------------------------------------------------------------------------
// monotone uint encoding of float for atomicMax-based segment max
// ---------------------------------------------------------------------------
__device__ __forceinline__ unsigned int enc_f32(float f) {
    unsigned int u = __float_as_uint(f);
    return (u & 0x80000000u) ? ~u : (u | 0x80000000u);
}
__device__ __forceinline__ float dec_f32(unsigned int u) {
    unsigned int b = (u & 0x80000000u) ? (u & 0x7FFFFFFFu) : ~u;
    return __uint_as_float(b);
}

// ---------------------------------------------------------------------------
// Kernel 2 (E1): per-edge attention logit + segment max.
// 32 lanes per edge; each lane covers 4 channels via float4.
// ---------------------------------------------------------------------------
__global__ __launch_bounds__(256) void edge_e_kernel(
    const int* __restrict__ ei, const int* __restrict__ etype,
    const float* __restrict__ hall, const float* __restrict__ att,
    float* __restrict__ e_out, unsigned int* __restrict__ segmax)
{
    const int lane = threadIdx.x & 31;
    const int eidx = (blockIdx.x * 256 + threadIdx.x) >> 5;
    if (eidx >= N_EDGES) return;
    const int src = ei[eidx];
    const int dst = ei[N_EDGES + eidx];
    const int t = etype[eidx];

    const float4 hs = *(const float4*)&hall[((size_t)src * 2 + t) * 128 + lane * 4];
    const float4 hd = *(const float4*)&hall[((size_t)dst * 2 + t) * 128 + lane * 4];
    const float4 al = *(const float4*)&att[(size_t)t * 256 + lane * 4];
    const float4 ar = *(const float4*)&att[(size_t)t * 256 + 128 + lane * 4];

    float s = hs.x * al.x + hs.y * al.y + hs.z * al.z + hs.w * al.w
            + hd.x * ar.x + hd.y * ar.y + hd.z * ar.z + hd.w * ar.w;
    #pragma unroll
    for (int off = 16; off; off >>= 1) s += __shfl_xor(s, off, 32);

    if (lane == 0) {
        s = (s > 0.f) ? s : NEG_SLOPE * s;   // leaky relu
        e_out[eidx] = s;
        atomicMax(&segmax[dst], enc_f32(s));
    }
}

// ---------------------------------------------------------------------------
// Kernel 3 (E2): ex = exp(e - segmax[dst]); denom[dst] += ex  (1 thread/edge)
// ---------------------------------------------------------------------------
__global__ __launch_bounds__(256) void edge_softmax_kernel(
    const int* __restrict__ ei, float* __restrict__ e_inout,
    const unsigned int* __restrict__ segmax, float* __restrict__ denom)
{
    const int i = blockIdx.x * 256 + threadIdx.x;
    if (i >= N_EDGES) return;
    const int dst = ei[N_EDGES + i];
    const float m = dec_f32(segmax[dst]);
    const float ex = expf(e_inout[i] - m);
    e_inout[i] = ex;
    atomicAdd(&denom[dst], ex);
}

// ---------------------------------------------------------------------------
// Kernel 4 (E3): out[dst] += h_src * (ex / (denom[dst] + eps))
// 32 lanes per edge, 4 scalar atomic adds per lane.
// ---------------------------------------------------------------------------
__global__ __launch_bounds__(256) void edge_scatter_kernel(
    const int* __restrict__ ei, const int* __restrict__ etype,
    const float* __restrict__ hall, const float* __restrict__ ex,
    const float* __restrict__ denom, float* __restrict__ out)
{
    const int lane = threadIdx.x & 31;
    const int eidx = (blockIdx.x * 256 + threadIdx.x) >> 5;
    if (eidx >= N_EDGES) return;
    const int src = ei[eidx];
    const int dst = ei[N_EDGES + eidx];
    const int t = etype[eidx];

    const float alpha = ex[eidx] / (denom[dst] + EPS_F);
    const float4 hs = *(const float4*)&hall[((size_t)src * 2 + t) * 128 + lane * 4];
    float* op = &out[(size_t)dst * 128 + lane * 4];
    atomicAdd(op + 0, hs.x * alpha);
    atomicAdd(op + 1, hs.y * alpha);
    atomicAdd(op + 2, hs.z * alpha);
    atomicAdd(op + 3, hs.w * alpha);
}

// ---------------------------------------------------------------------------
extern "C" void kernel_launch(void* const* d_in, const int* in_sizes, int n_in,
                              void* d_out, int out_size, void* d_ws, size_t ws_size,
                              hipStream_t stream) {
    const float* x      = (const float*)d_in[0];
    const int*   ei     = (const int*)d_in[1];
    const int*   etype  = (const int*)d_in[2];
    const float* weight = (const float*)d_in[3];
    const float* att    = (const float*)d_in[4];
    const float* root_w = (const float*)d_in[5];
    const float* root_b = (const float*)d_in[6];
    float* out = (float*)d_out;

    // workspace layout (floats): hall [N*2*128] | e/ex [E] | segmax [N] | denom [N]
    float* ws = (float*)d_ws;
    float* hall = ws;
    float* e    = hall + (size_t)N_NODES * 2 * 128;
    unsigned int* segmax = (unsigned int*)(e + N_EDGES);
    float* denom = (float*)(segmax + N_NODES);

    // zero segmax (0 == encoded -inf floor) and denom in one contiguous memset
    hipMemsetAsync(segmax, 0, sizeof(unsigned int) * (size_t)N_NODES * 2, stream);

    gemm_kernel<<<(N_NODES + TM - 1) / TM, 256, 0, stream>>>(
        x, weight, root_w, root_b, hall, out);

    edge_e_kernel<<<(N_EDGES * 32) / 256, 256, 0, stream>>>(
        ei, etype, hall, att, e, segmax);

    edge_softmax_kernel<<<(N_EDGES + 255) / 256, 256, 0, stream>>>(
        ei, e, segmax, denom);

    edge_scatter_kernel<<<(N_EDGES * 32) / 256, 256, 0, stream>>>(
        ei, etype, hall, e, denom, out);
}

// Round 4
// 334.314 us; speedup vs baseline: 3.3995x; 3.3995x over previous
//
#include <hip/hip_runtime.h>
#include <hip/hip_bf16.h>

#define N_NODES 50000
#define N_EDGES 500000
#define IN_CH 128
#define OUT_CH 128
#define N_TYPES 2
#define NEG_SLOPE 0.2f
#define EPS_F 1e-16f

// ---------------------------------------------------------------------------
// Kernel 1: fused GEMM
//   hall[n][t][o] = sum_k x[n][k] * weight[t][k][o]      (t = 0,1)
//   out[n][o]     = sum_k x[n][k] * root_w[o][k] + root_b[o]
// ---------------------------------------------------------------------------
#define TM 32
#define BS_STRIDE 132

__global__ __launch_bounds__(256) void gemm_kernel(
    const float* __restrict__ x, const float* __restrict__ weight,
    const float* __restrict__ root_w, const float* __restrict__ root_b,
    float* __restrict__ hall, float* __restrict__ out)
{
    __shared__ float xs[TM][IN_CH];
    __shared__ float Bs[64][BS_STRIDE];

    const int tid = threadIdx.x;
    const int block_n0 = blockIdx.x * TM;
    const int nb = tid >> 5;
    const int ob = tid & 31;
    const int n0 = nb * 4;
    const int o0 = ob * 4;

    {
        const float4* xg = (const float4*)x;
        #pragma unroll
        for (int i = 0; i < 4; ++i) {
            int idx = tid + i * 256;
            int n = idx >> 5;
            int c4 = idx & 31;
            int gn = block_n0 + n;
            float4 v = make_float4(0.f, 0.f, 0.f, 0.f);
            if (gn < N_NODES) v = xg[(size_t)gn * 32 + c4];
            *(float4*)&xs[n][c4 * 4] = v;
        }
    }

    for (int c = 0; c < 3; ++c) {
        float acc[4][4] = {};
        for (int kh = 0; kh < 2; ++kh) {
            __syncthreads();
            if (c < 2) {
                const float4* wg =
                    (const float4*)(weight + (size_t)c * IN_CH * OUT_CH + (size_t)kh * 64 * OUT_CH);
                #pragma unroll
                for (int i = 0; i < 8; ++i) {
                    int idx = tid + i * 256;
                    int kk = idx >> 5;
                    int c4 = idx & 31;
                    float4 v = wg[kk * 32 + c4];
                    *(float4*)&Bs[kk][c4 * 4] = v;
                }
            } else {
                for (int i = 0; i < 32; ++i) {
                    int idx = tid + i * 256;
                    int j = idx >> 6;
                    int kk = idx & 63;
                    Bs[kk][j] = root_w[(size_t)j * IN_CH + kh * 64 + kk];
                }
            }
            __syncthreads();

            #pragma unroll 4
            for (int kk = 0; kk < 64; ++kk) {
                float4 bv = *(const float4*)&Bs[kk][o0];
                float x0 = xs[n0 + 0][kh * 64 + kk];
                float x1 = xs[n0 + 1][kh * 64 + kk];
                float x2 = xs[n0 + 2][kh * 64 + kk];
                float x3 = xs[n0 + 3][kh * 64 + kk];
                acc[0][0] += x0 * bv.x; acc[0][1] += x0 * bv.y; acc[0][2] += x0 * bv.z; acc[0][3] += x0 * bv.w;
                acc[1][0] += x1 * bv.x; acc[1][1] += x1 * bv.y; acc[1][2] += x1 * bv.z; acc[1][3] += x1 * bv.w;
                acc[2][0] += x2 * bv.x; acc[2][1] += x2 * bv.y; acc[2][2] += x2 * bv.z; acc[2][3] += x2 * bv.w;
                acc[3][0] += x3 * bv.x; acc[3][1] += x3 * bv.y; acc[3][2] += x3 * bv.z; acc[3][3] += x3 * bv.w;
            }
        }

        if (c < 2) {
            #pragma unroll
            for (int i = 0; i < 4; ++i) {
                int gn = block_n0 + n0 + i;
                if (gn < N_NODES) {
                    float4 v = make_float4(acc[i][0], acc[i][1], acc[i][2], acc[i][3]);
                    *(float4*)&hall[((size_t)gn * 2 + c) * 128 + o0] = v;
                }
            }
        } else {
            float4 bias = *(const float4*)&root_b[o0];
            #pragma unroll
            for (int i = 0; i < 4; ++i) {
                int gn = block_n0 + n0 + i;
                if (gn < N_NODES) {
                    float4 v = make_float4(acc[i][0] + bias.x, acc[i][1] + bias.y,
                                           acc[i][2] + bias.z, acc[i][3] + bias.w);
                    *(float4*)&out[(size_t)gn * 128 + o0] = v;
                }
            }
        }
    }
}

// ---------------------------------------------------------------------------
// CSR build: histogram -> block scan -> block-sum scan -> add -> scatter ids
// ---------------------------------------------------------------------------
__global__ __launch_bounds__(256) void hist_kernel(
    const int* __restrict__ ei, int* __restrict__ deg)
{
    int i = blockIdx.x * 256 + threadIdx.x;
    if (i < N_EDGES) atomicAdd(&deg[ei[N_EDGES + i]], 1);
}

__global__ __launch_bounds__(256) void scan1_kernel(
    const int* __restrict__ deg, int* __restrict__ rp, int* __restrict__ bsum)
{
    __shared__ int s[256];
    int i = blockIdx.x * 256 + threadIdx.x;
    int v = (i < N_NODES) ? deg[i] : 0;
    s[threadIdx.x] = v;
    __syncthreads();
    #pragma unroll
    for (int off = 1; off < 256; off <<= 1) {
        int t = (threadIdx.x >= off) ? s[threadIdx.x - off] : 0;
        __syncthreads();
        s[threadIdx.x] += t;
        __syncthreads();
    }
    if (i < N_NODES) rp[i + 1] = s[threadIdx.x];   // inclusive, local to block
    if (threadIdx.x == 255) bsum[blockIdx.x] = s[255];
    if (i == 0) rp[0] = 0;
}

__global__ __launch_bounds__(256) void scan2_kernel(int* __restrict__ bsum, int nb)
{
    __shared__ int s[256];
    int tid = threadIdx.x;
    int v = (tid < nb) ? bsum[tid] : 0;
    s[tid] = v;
    __syncthreads();
    #pragma unroll
    for (int off = 1; off < 256; off <<= 1) {
        int t = (tid >= off) ? s[tid - off] : 0;
        __syncthreads();
        s[tid] += t;
        __syncthreads();
    }
    if (tid < nb) bsum[tid] = s[tid] - v;          // exclusive
}

__global__ __launch_bounds__(256) void scan3_kernel(
    int* __restrict__ rp, const int* __restrict__ bsum)
{
    int i = blockIdx.x * 256 + threadIdx.x;
    if (i < N_NODES) rp[i + 1] += bsum[blockIdx.x];
}

__global__ __launch_bounds__(256) void csr_scatter_kernel(
    const int* __restrict__ ei, const int* __restrict__ etype,
    const int* __restrict__ rp, int* __restrict__ cursor, int* __restrict__ skey)
{
    int i = blockIdx.x * 256 + threadIdx.x;
    if (i >= N_EDGES) return;
    int dst = ei[N_EDGES + i];
    int pos = rp[dst] + atomicAdd(&cursor[dst], 1);
    skey[pos] = (ei[i] << 1) | (etype[i] & 1);
}

// ---------------------------------------------------------------------------
// Fused per-node kernel: one wave (64 lanes, 2 ch/lane) per node.
// Online softmax over incoming edges; single h_src gather per edge.
// ---------------------------------------------------------------------------
__global__ __launch_bounds__(256) void node_agg_kernel(
    const int* __restrict__ rp, const int* __restrict__ skey,
    const float* __restrict__ hall, const float* __restrict__ att,
    float* __restrict__ out)
{
    const int lane = threadIdx.x & 63;
    const int node = (blockIdx.x * 256 + threadIdx.x) >> 6;
    if (node >= N_NODES) return;
    const int row0 = rp[node], row1 = rp[node + 1];
    if (row0 == row1) return;   // out keeps root contribution

    // attention vectors (2 channels per lane, both types) in registers
    const float2 al0 = *(const float2*)&att[0 * 256 + lane * 2];
    const float2 ar0 = *(const float2*)&att[0 * 256 + 128 + lane * 2];
    const float2 al1 = *(const float2*)&att[1 * 256 + lane * 2];
    const float2 ar1 = *(const float2*)&att[1 * 256 + 128 + lane * 2];

    // per-node dst-side logit contribution, both types, reduced across wave
    const float2 hd0 = *(const float2*)&hall[((size_t)node * 2 + 0) * 128 + lane * 2];
    const float2 hd1 = *(const float2*)&hall[((size_t)node * 2 + 1) * 128 + lane * 2];
    float dr0 = hd0.x * ar0.x + hd0.y * ar0.y;
    float dr1 = hd1.x * ar1.x + hd1.y * ar1.y;
    #pragma unroll
    for (int off = 32; off; off >>= 1) {
        dr0 += __shfl_xor(dr0, off);
        dr1 += __shfl_xor(dr1, off);
    }

    float m = -__builtin_inff();
    float denom = 0.f, a0 = 0.f, a1 = 0.f;
    for (int j = row0; j < row1; ++j) {
        const int key = skey[j];            // broadcast load (uniform in wave)
        const int t = key & 1;
        const float2 h = *(const float2*)&hall[((size_t)(key >> 1) * 2 + t) * 128 + lane * 2];
        const float2 al = t ? al1 : al0;
        float p = h.x * al.x + h.y * al.y;
        #pragma unroll
        for (int off = 32; off; off >>= 1) p += __shfl_xor(p, off);
        float ecur = p + (t ? dr1 : dr0);
        ecur = (ecur > 0.f) ? ecur : NEG_SLOPE * ecur;   // leaky relu
        if (ecur > m) {                      // wave-uniform branch
            const float r = __expf(m - ecur);   // exp(-inf)=0 handles first edge
            denom *= r; a0 *= r; a1 *= r;
            m = ecur;
        }
        const float w = __expf(ecur - m);
        denom += w;
        a0 += w * h.x;
        a1 += w * h.y;
    }
    const float inv = 1.f / (denom + EPS_F);
    float* op = &out[(size_t)node * 128 + lane * 2];
    op[0] += a0 * inv;
    op[1] += a1 * inv;
}

// ---------------------------------------------------------------------------
extern "C" void kernel_launch(void* const* d_in, const int* in_sizes, int n_in,
                              void* d_out, int out_size, void* d_ws, size_t ws_size,
                              hipStream_t stream) {
    const float* x      = (const float*)d_in[0];
    const int*   ei     = (const int*)d_in[1];
    const int*   etype  = (const int*)d_in[2];
    const float* weight = (const float*)d_in[3];
    const float* att    = (const float*)d_in[4];
    const float* root_w = (const float*)d_in[5];
    const float* root_b = (const float*)d_in[6];
    float* out = (float*)d_out;

    // ws layout: hall [N*2*128] f32 | deg [N] | cursor [N] | rp [N+1] | bsum [256] | skey [E]
    float* hall  = (float*)d_ws;
    int* deg     = (int*)(hall + (size_t)N_NODES * 2 * 128);
    int* cursor  = deg + N_NODES;
    int* rp      = cursor + N_NODES;
    int* bsum    = rp + (N_NODES + 1);
    int* skey    = bsum + 256;

    const int NB_E = (N_EDGES + 255) / 256;   // 1954
    const int NB_N = (N_NODES + 255) / 256;   // 196

    // zero deg + cursor in one contiguous memset
    hipMemsetAsync(deg, 0, sizeof(int) * (size_t)N_NODES * 2, stream);

    gemm_kernel<<<(N_NODES + TM - 1) / TM, 256, 0, stream>>>(
        x, weight, root_w, root_b, hall, out);

    hist_kernel<<<NB_E, 256, 0, stream>>>(ei, deg);
    scan1_kernel<<<NB_N, 256, 0, stream>>>(deg, rp, bsum);
    scan2_kernel<<<1, 256, 0, stream>>>(bsum, NB_N);
    scan3_kernel<<<NB_N, 256, 0, stream>>>(rp, bsum);
    csr_scatter_kernel<<<NB_E, 256, 0, stream>>>(ei, etype, rp, cursor, skey);

    node_agg_kernel<<<(N_NODES + 3) / 4, 256, 0, stream>>>(
        rp, skey, hall, att, out);
}